// Round 6
// baseline (697.573 us; speedup 1.0000x reference)
//
#include <hip/hip_runtime.h>
#include <math.h>

#define Mv 8
#define Nv 8192
#define Kv 256
#define BPM 64            // blocks per m -> 512 blocks total (2/CU, all resident)
#define NBLK (Mv*BPM)
#define NITER 6
#define EPSILON_C 0.01f
#define GAMMA_C 0.005f

// ws layout (float offsets)
#define WS_R     0        // 72   (M x 3 x 3 row-major)
#define WS_T     72       // 24   (M x 3)
#define WS_X     96       // 768  (K x 3)
#define WS_Q     864      // 256
#define WS_BETA  1120     // 1
#define WS_BAR   1124     // 2 u32 (barrier count, generation)
#define WS_ACC   1128     // 3 x ACCSZ accumulator buffers
// within an ACC buffer:
#define AC_STATS 0        // 128 (M x 16)
#define AC_L     128      // 2048 (M x K)
#define AC_W     2176     // 6144 (M x 3 x K)
#define AC_H     8320     // 2048 (M x K)
#define ACCSZ    10368

// ---- wave-wide sum via DPP; wave-uniform result. All lanes must be active.
__device__ __forceinline__ float wave_red_sum(float x) {
  int v;
  float t;
  v = __builtin_bit_cast(int, x);
  t = __builtin_bit_cast(float, __builtin_amdgcn_update_dpp(0, v, 0x111, 0xf, 0xf, true));  // row_shr:1
  x += t; v = __builtin_bit_cast(int, x);
  t = __builtin_bit_cast(float, __builtin_amdgcn_update_dpp(0, v, 0x112, 0xf, 0xf, true));  // row_shr:2
  x += t; v = __builtin_bit_cast(int, x);
  t = __builtin_bit_cast(float, __builtin_amdgcn_update_dpp(0, v, 0x114, 0xf, 0xf, true));  // row_shr:4
  x += t; v = __builtin_bit_cast(int, x);
  t = __builtin_bit_cast(float, __builtin_amdgcn_update_dpp(0, v, 0x118, 0xf, 0xf, true));  // row_shr:8
  x += t; v = __builtin_bit_cast(int, x);
  t = __builtin_bit_cast(float, __builtin_amdgcn_update_dpp(0, v, 0x142, 0xa, 0xf, false)); // row_bcast:15
  x += t; v = __builtin_bit_cast(int, x);
  t = __builtin_bit_cast(float, __builtin_amdgcn_update_dpp(0, v, 0x143, 0xc, 0xf, false)); // row_bcast:31
  x += t;
  return __builtin_bit_cast(float, __builtin_amdgcn_readlane(__builtin_bit_cast(int, x), 63));
}

// ---- device-scope sense-reversing grid barrier (thread 0 per block spins).
// Agent-scope acq_rel/acquire/release handle cross-XCD L2 writeback/invalidate.
__device__ __forceinline__ void grid_barrier(unsigned* cnt, unsigned* gen) {
  __syncthreads();
  if (threadIdx.x == 0) {
    unsigned g = __hip_atomic_load(gen, __ATOMIC_RELAXED, __HIP_MEMORY_SCOPE_AGENT);
    unsigned a = __hip_atomic_fetch_add(cnt, 1u, __ATOMIC_ACQ_REL, __HIP_MEMORY_SCOPE_AGENT);
    if (a == (unsigned)(NBLK - 1)) {
      __hip_atomic_store(cnt, 0u, __ATOMIC_RELAXED, __HIP_MEMORY_SCOPE_AGENT);
      __hip_atomic_store(gen, g + 1u, __ATOMIC_RELEASE, __HIP_MEMORY_SCOPE_AGENT);
    } else {
      while (__hip_atomic_load(gen, __ATOMIC_ACQUIRE, __HIP_MEMORY_SCOPE_AGENT) == g)
        __builtin_amdgcn_s_sleep(2);
    }
  }
  __syncthreads();
}

// ---------------------------------------------------------------- init
__global__ __launch_bounds__(256) void p0_init(const float* __restrict__ Vs,
                                               const float* __restrict__ X0,
                                               const float* __restrict__ Q0,
                                               float* __restrict__ ws) {
  __shared__ float sred[4];
  int tid = threadIdx.x;
  int b = blockIdx.x;
  int wave = tid >> 6, lane = tid & 63;
  if (b < 24) {
    int m = b / 3, d = b % 3;
    const float* src = Vs + (size_t)(m*3 + d) * Nv;
    float s = 0.f;
    for (int n = tid; n < Nv; n += 256) s += src[n];
    s = wave_red_sum(s);
    if (lane == 0) sred[wave] = s;
    __syncthreads();
    if (tid == 0) {
      float tot = sred[0]+sred[1]+sred[2]+sred[3];
      ws[WS_T + m*3 + d] = -tot / (float)Nv;
    }
    if (d == 0 && tid < 9) {
      ws[WS_R + m*9 + tid] = (tid==0||tid==4||tid==8) ? 1.f : 0.f;
    }
  } else {
    float s = (tid < Kv) ? Q0[tid] : 0.f;
    s = wave_red_sum(s);
    if (lane == 0) sred[wave] = s;
    __syncthreads();
    if (tid == 0) {
      float mq = (sred[0]+sred[1]+sred[2]+sred[3]) / (float)Kv;
      ws[WS_BETA] = GAMMA_C * mq * sqrtf(mq);
    }
    if (tid < Kv) ws[WS_Q + tid] = Q0[tid];
    for (int i = tid; i < Kv*3; i += 256) ws[WS_X + i] = X0[i];
    // zero barrier state + ACC buffer 0 (buffers 1,2 zeroed inside p_main)
    for (int i = tid; i < 2 + ACCSZ; i += 256) ws[WS_BAR + i] = 0.f;
  }
}

// ---- fp32 Jacobi rotation, COMPILE-TIME pair, named scalars only.
#define JROTF(app,aqq,apq,apr,aqr, vp0,vp1,vp2, vq0,vq1,vq2) do {           \
    float tau_ = (aqq - app) * __builtin_amdgcn_rcpf(2.0f*apq);             \
    float tt_ = __builtin_amdgcn_rcpf(fabsf(tau_) +                         \
                   __builtin_amdgcn_sqrtf(fmaf(tau_,tau_,1.0f)));           \
    tt_ = (tau_ < 0.0f) ? -tt_ : tt_;                                       \
    tt_ = (apq == 0.0f) ? 0.0f : tt_;                                       \
    float c_ = __builtin_amdgcn_rsqf(fmaf(tt_,tt_,1.0f)), s_ = tt_*c_;      \
    float papq_ = apq;                                                      \
    app = fmaf(-tt_,papq_,app); aqq = fmaf(tt_,papq_,aqq); apq = 0.0f;      \
    float tp_ = apr, tq_ = aqr;                                             \
    apr = c_*tp_ - s_*tq_; aqr = s_*tp_ + c_*tq_;                           \
    tp_=vp0; tq_=vq0; vp0=c_*tp_-s_*tq_; vq0=s_*tp_+c_*tq_;                 \
    tp_=vp1; tq_=vq1; vp1=c_*tp_-s_*tq_; vq1=s_*tp_+c_*tq_;                 \
    tp_=vp2; tq_=vq2; vp2=c_*tp_-s_*tq_; vq2=s_*tp_+c_*tq_;                 \
  } while(0)

#define CSWAP3F(la,lb, a0,a1,a2, b0,b1,b2) do {                             \
    if (la < lb) { float t_;                                                \
      t_=la; la=lb; lb=t_; t_=a0; a0=b0; b0=t_;                             \
      t_=a1; a1=b1; b1=t_; t_=a2; a2=b2; b2=t_; }                           \
  } while(0)

// ---------------------------------------------- persistent all-iterations kernel
// 512 blocks (2/CU, all co-resident). Per iteration: phase A accumulates
// L/W/H + 16 per-m stats into the triple-buffered global acc via atomics;
// ONE grid barrier; phase B (redundant in every block) rebuilds R/t (8-lane
// fp32 polar solve) and the per-k X/Q update into block-local LDS. Buffer
// (it+1)%3 is zeroed during phase A(it) — its last reader was B(it-2),
// strictly before bar(it-1). p2's ~30us/dispatch floor (R2-R5: content-
// insensitive) is deleted by never dispatching a tiny kernel at all.
__global__ __launch_bounds__(256, 2) void p_main(const float* __restrict__ Vs,
                                                 float* __restrict__ ws) {
  __shared__ float sb[4][5][Kv]; // 20 KB
  __shared__ float st4[4][16];
  __shared__ float sX[Kv][3];
  __shared__ float sQ[Kv];
  __shared__ float sR[Mv][9];
  __shared__ float sT[Mv][3];
  __shared__ float sTn[Mv];

  int tid  = threadIdx.x;
  int wave = tid >> 6, lane = tid & 63;
  int bid  = blockIdx.x;
  int m    = bid / BPM;
  int blk  = bid % BPM;
  int wid  = blk*4 + wave;   // 0..255 within this m
  const int k = tid;

  // bootstrap LDS from p0's ws
  if (tid < 72) ((float*)sR)[tid] = ws[WS_R + tid];
  if (tid < 24) ((float*)sT)[tid] = ws[WS_T + tid];
  sX[k][0] = ws[WS_X + 3*k+0];
  sX[k][1] = ws[WS_X + 3*k+1];
  sX[k][2] = ws[WS_X + 3*k+2];
  sQ[k]    = ws[WS_Q + k];
  float beta = ws[WS_BETA];

  unsigned* bar = (unsigned*)(ws + WS_BAR);
  const float* V0 = Vs + (size_t)(m*3+0)*Nv;
  const float* V1 = Vs + (size_t)(m*3+1)*Nv;
  const float* V2 = Vs + (size_t)(m*3+2)*Nv;

  for (int it = 0; it < NITER; ++it) {
    __syncthreads();   // sX/sQ/sR/sT writes (prev B / bootstrap) -> A reads
    float* acc  = ws + WS_ACC + (it % 3)*ACCSZ;
    float* accn = ws + WS_ACC + ((it+1) % 3)*ACCSZ;
    { // partitioned zero of next buffer (21 els/block; flushed by bar release)
      int base = bid*21;
      if (tid < 21 && base + tid < ACCSZ) accn[base + tid] = 0.f;
    }
    // ---- phase A
    float R00=sR[m][0],R01=sR[m][1],R02=sR[m][2];
    float R10=sR[m][3],R11=sR[m][4],R12=sR[m][5];
    float R20=sR[m][6],R21=sR[m][7],R22=sR[m][8];
    float t0=sT[m][0], t1=sT[m][1], t2=sT[m][2];
    float kXx[4],kXy[4],kXz[4],kA[4],kB[4],kQ[4],kQ32[4];
    #pragma unroll
    for (int j=0;j<4;j++) {
      int kk = lane + 64*j;
      float xx = sX[kk][0], xy = sX[kk][1], xz = sX[kk][2];
      float q  = sQ[kk];
      kXx[j]=xx; kXy[j]=xy; kXz[j]=xz;
      kA[j]  = -0.5f*q;
      kB[j]  = kA[j]*(xx*xx+xy*xy+xz*xz);
      kQ[j]  = q;
      kQ32[j]= q*sqrtf(q);
    }
    float aL[4]={0,0,0,0}, aWx[4]={0,0,0,0}, aWy[4]={0,0,0,0},
          aWz[4]={0,0,0,0}, aH[4]={0,0,0,0};
    for (int n = wid; n < Nv; n += 256) {
      float vx = V0[n], vy = V1[n], vz = V2[n];
      float px = fmaf(R00,vx, fmaf(R01,vy, fmaf(R02,vz, t0)));
      float py = fmaf(R10,vx, fmaf(R11,vy, fmaf(R12,vz, t1)));
      float pz = fmaf(R20,vx, fmaf(R21,vy, fmaf(R22,vz, t2)));
      float tvn = fmaf(px,px, fmaf(py,py, pz*pz));
      float vn  = fmaf(vx,vx, fmaf(vy,vy, vz*vz));
      float ap[4]; float s = 0.f;
      #pragma unroll
      for (int j=0;j<4;j++) {
        float dot = fmaf(px,kXx[j], fmaf(py,kXy[j], pz*kXz[j]));
        float arg = fmaf(kQ[j], dot, fmaf(kA[j], tvn, kB[j]));
        float e = __expf(arg)*kQ32[j];
        ap[j] = e; s += e;
      }
      float S = wave_red_sum(s);
      float inv = 1.f/(S + beta);
      #pragma unroll
      for (int j=0;j<4;j++) {
        float a = ap[j]*inv;
        aL[j] += a;
        aWx[j] = fmaf(a,vx,aWx[j]);
        aWy[j] = fmaf(a,vy,aWy[j]);
        aWz[j] = fmaf(a,vz,aWz[j]);
        aH[j]  = fmaf(a,vn,aH[j]);
      }
    }
    #pragma unroll
    for (int j=0;j<4;j++) {
      int kk = lane + 64*j;
      sb[wave][0][kk]=aL[j];  sb[wave][1][kk]=aWx[j]; sb[wave][2][kk]=aWy[j];
      sb[wave][3][kk]=aWz[j]; sb[wave][4][kk]=aH[j];
    }
    __syncthreads();
    float vL  = sb[0][0][k]+sb[1][0][k]+sb[2][0][k]+sb[3][0][k];
    float vWx = sb[0][1][k]+sb[1][1][k]+sb[2][1][k]+sb[3][1][k];
    float vWy = sb[0][2][k]+sb[1][2][k]+sb[2][2][k]+sb[3][2][k];
    float vWz = sb[0][3][k]+sb[1][3][k]+sb[2][3][k]+sb[3][3][k];
    float vH  = sb[0][4][k]+sb[1][4][k]+sb[2][4][k]+sb[3][4][k];
    atomicAdd(&acc[AC_L + m*Kv + k], vL);
    atomicAdd(&acc[AC_W + (m*3+0)*Kv + k], vWx);
    atomicAdd(&acc[AC_W + (m*3+1)*Kv + k], vWy);
    atomicAdd(&acc[AC_W + (m*3+2)*Kv + k], vWz);
    atomicAdd(&acc[AC_H + m*Kv + k], vH);
    // block-partial 16 stats for this m
    {
      float q  = sQ[k];
      float x0 = sX[k][0], x1 = sX[k][1], x2 = sX[k][2];
      float bk = vL*q;
      float sw0 = vWx*q, sw1 = vWy*q, sw2 = vWz*q;
      float pr[16];
      pr[0]=bk;  pr[1]=bk*x0; pr[2]=bk*x1; pr[3]=bk*x2;
      pr[4]=sw0; pr[5]=sw1;   pr[6]=sw2;
      pr[7]=sw0*x0;  pr[8]=sw1*x0;  pr[9]=sw2*x0;
      pr[10]=sw0*x1; pr[11]=sw1*x1; pr[12]=sw2*x1;
      pr[13]=sw0*x2; pr[14]=sw1*x2; pr[15]=sw2*x2;
      float red[16];
      #pragma unroll
      for (int v2=0; v2<16; v2++) red[v2] = wave_red_sum(pr[v2]);
      if (lane == 0) {
        #pragma unroll
        for (int v2=0; v2<16; v2++) st4[wave][v2] = red[v2];
      }
      __syncthreads();
      if (k < 16)
        atomicAdd(&acc[AC_STATS + m*16 + k],
                  st4[0][k]+st4[1][k]+st4[2][k]+st4[3][k]);
    }
    // ---- all atomics visible after this
    grid_barrier(bar, bar + 1);

    // ---- phase B (redundant per block)
    float lk[Mv], w0v[Mv], w1v[Mv], w2v[Mv], hk[Mv];
    #pragma unroll
    for (int mm=0;mm<Mv;mm++) {
      lk[mm]  = acc[AC_L + mm*Kv + k];
      w0v[mm] = acc[AC_W + (mm*3+0)*Kv + k];
      w1v[mm] = acc[AC_W + (mm*3+1)*Kv + k];
      w2v[mm] = acc[AC_W + (mm*3+2)*Kv + k];
      hk[mm]  = acc[AC_H + mm*Kv + k];
    }
    if (tid < Mv) {
      int mm = tid;
      const float* st = acc + AC_STATS + mm*16;
      float s0=st[0], s1=st[1], s2v=st[2], s3=st[3], s4=st[4], s5=st[5],
            s6=st[6], s7=st[7], s8=st[8], s9=st[9], s10=st[10], s11=st[11],
            s12=st[12], s13=st[13], s14=st[14], s15=st[15];
      float z = s0;
      float mX0 = s1, mX1 = s2v, mX2 = s3;
      float mW0 = s4, mW1 = s5, mW2 = s6;
      float iz = 1.0f/z;
      float P00 = s7  - mX0*mW0*iz;
      float P01 = s8  - mX0*mW1*iz;
      float P02 = s9  - mX0*mW2*iz;
      float P10 = s10 - mX1*mW0*iz;
      float P11 = s11 - mX1*mW1*iz;
      float P12 = s12 - mX1*mW2*iz;
      float P20 = s13 - mX2*mW0*iz;
      float P21 = s14 - mX2*mW1*iz;
      float P22 = s15 - mX2*mW2*iz;
      float a00 = P00*P00 + P10*P10 + P20*P20;
      float a01 = P00*P01 + P10*P11 + P20*P21;
      float a02 = P00*P02 + P10*P12 + P20*P22;
      float a11 = P01*P01 + P11*P11 + P21*P21;
      float a12 = P01*P02 + P11*P12 + P21*P22;
      float a22 = P02*P02 + P12*P12 + P22*P22;
      float v00=1, v01=0, v02=0, v10=0, v11=1, v12=0, v20=0, v21=0, v22=1;
      #pragma unroll 1
      for (int sweep = 0; sweep < 8; sweep++) {
        JROTF(a00,a11,a01, a02,a12, v00,v10,v20, v01,v11,v21);
        JROTF(a00,a22,a02, a01,a12, v00,v10,v20, v02,v12,v22);
        JROTF(a11,a22,a12, a01,a02, v01,v11,v21, v02,v12,v22);
      }
      float l0 = a00, l1 = a11, l2 = a22;
      CSWAP3F(l0,l1, v00,v10,v20, v01,v11,v21);
      CSWAP3F(l1,l2, v01,v11,v21, v02,v12,v22);
      CSWAP3F(l0,l1, v00,v10,v20, v01,v11,v21);
      float detP = P00*(P11*P22-P12*P21) - P01*(P10*P22-P12*P20)
                 + P02*(P10*P21-P11*P20);
      float s2d = (detP < 0.0f) ? -1.0f : 1.0f;
      float tiny = 1e-18f*l0 + 1e-30f;
      float w0i = __builtin_amdgcn_rsqf(fmaxf(l0,tiny));
      float w1i = __builtin_amdgcn_rsqf(fmaxf(l1,tiny));
      float w2i = s2d*__builtin_amdgcn_rsqf(fmaxf(l2,tiny));
      float M00 = w0i*v00*v00 + w1i*v01*v01 + w2i*v02*v02;
      float M01 = w0i*v00*v10 + w1i*v01*v11 + w2i*v02*v12;
      float M02 = w0i*v00*v20 + w1i*v01*v21 + w2i*v02*v22;
      float M11 = w0i*v10*v10 + w1i*v11*v11 + w2i*v12*v12;
      float M12 = w0i*v10*v20 + w1i*v11*v21 + w2i*v12*v22;
      float M22 = w0i*v20*v20 + w1i*v21*v21 + w2i*v22*v22;
      float R00n = P00*M00 + P01*M01 + P02*M02;
      float R01n = P00*M01 + P01*M11 + P02*M12;
      float R02n = P00*M02 + P01*M12 + P02*M22;
      float R10n = P10*M00 + P11*M01 + P12*M02;
      float R11n = P10*M01 + P11*M11 + P12*M12;
      float R12n = P10*M02 + P11*M12 + P12*M22;
      float R20n = P20*M00 + P21*M01 + P22*M02;
      float R21n = P20*M01 + P21*M11 + P22*M12;
      float R22n = P20*M02 + P21*M12 + P22*M22;
      float tm0 = (mX0 - (R00n*mW0 + R01n*mW1 + R02n*mW2))*iz;
      float tm1 = (mX1 - (R10n*mW0 + R11n*mW1 + R12n*mW2))*iz;
      float tm2 = (mX2 - (R20n*mW0 + R21n*mW1 + R22n*mW2))*iz;
      sR[mm][0]=R00n; sR[mm][1]=R01n; sR[mm][2]=R02n;
      sR[mm][3]=R10n; sR[mm][4]=R11n; sR[mm][5]=R12n;
      sR[mm][6]=R20n; sR[mm][7]=R21n; sR[mm][8]=R22n;
      sT[mm][0]=tm0; sT[mm][1]=tm1; sT[mm][2]=tm2;
      sTn[mm] = tm0*tm0 + tm1*tm1 + tm2*tm2;
    }
    __syncthreads();
    {
      float den = 0.f, Xn0=0.f, Xn1=0.f, Xn2=0.f, S2=0.f;
      #pragma unroll
      for (int mm=0;mm<Mv;mm++) {
        float r0 = sR[mm][0]*w0v[mm] + sR[mm][1]*w1v[mm] + sR[mm][2]*w2v[mm];
        float r1 = sR[mm][3]*w0v[mm] + sR[mm][4]*w1v[mm] + sR[mm][5]*w2v[mm];
        float r2 = sR[mm][6]*w0v[mm] + sR[mm][7]*w1v[mm] + sR[mm][8]*w2v[mm];
        float tt0 = sT[mm][0], tt1 = sT[mm][1], tt2 = sT[mm][2];
        den += lk[mm];
        Xn0 += r0 + tt0*lk[mm]; Xn1 += r1 + tt1*lk[mm]; Xn2 += r2 + tt2*lk[mm];
        S2  += hk[mm] + 2.f*(tt0*r0+tt1*r1+tt2*r2) + sTn[mm]*lk[mm];
      }
      float x0, x1, x2;
      if (it > 1) { float inv = 1.f/den; x0=Xn0*inv; x1=Xn1*inv; x2=Xn2*inv; }
      else        { x0=sX[k][0]; x1=sX[k][1]; x2=sX[k][2]; }
      float wn = S2 + (x0*x0+x1*x1+x2*x2)*den - 2.f*(x0*Xn0+x1*Xn1+x2*Xn2);
      float qn = 3.f*den / (wn + 3.f*den*EPSILON_C);
      sX[k][0]=x0; sX[k][1]=x1; sX[k][2]=x2;
      sQ[k] = qn;
    }
  }
  __syncthreads();
  // block 0 publishes final R/t/X for p3 (kernel boundary gives visibility)
  if (bid == 0) {
    if (tid < 72) ws[WS_R + tid] = ((float*)sR)[tid];
    if (tid < 24) ws[WS_T + tid] = ((float*)sT)[tid];
    ws[WS_X + 3*k+0] = sX[k][0];
    ws[WS_X + 3*k+1] = sX[k][1];
    ws[WS_X + 3*k+2] = sX[k][2];
  }
}

// ---------------------------------------------------------------- final out
__global__ __launch_bounds__(256) void p3_final(const float* __restrict__ Vs,
                                                const float* __restrict__ ws,
                                                float* __restrict__ out) {
  int idx = blockIdx.x*256 + threadIdx.x;
  if (idx < Mv*3*Nv) {
    int m = idx / (3*Nv);
    int r = idx % (3*Nv);
    int d = r / Nv;
    int n = r % Nv;
    float vx = Vs[(size_t)(m*3+0)*Nv + n];
    float vy = Vs[(size_t)(m*3+1)*Nv + n];
    float vz = Vs[(size_t)(m*3+2)*Nv + n];
    out[idx] = fmaf(ws[WS_R+m*9+d*3+0],vx,
               fmaf(ws[WS_R+m*9+d*3+1],vy,
               fmaf(ws[WS_R+m*9+d*3+2],vz, ws[WS_T+m*3+d])));
  } else if (idx < Mv*3*Nv + 72 + 24 + Kv*3) {
    int j = idx - Mv*3*Nv;
    float v;
    if (j < 72)      v = ws[WS_R + j];
    else if (j < 96) v = ws[WS_T + (j-72)];
    else             v = ws[WS_X + (j-96)];
    out[idx] = v;
  }
}

extern "C" void kernel_launch(void* const* d_in, const int* in_sizes, int n_in,
                              void* d_out, int out_size, void* d_ws, size_t ws_size,
                              hipStream_t stream) {
  const float* Vs = (const float*)d_in[0];
  const float* X0 = (const float*)d_in[1];
  const float* Q0 = (const float*)d_in[2];
  float* out = (float*)d_out;
  float* ws  = (float*)d_ws;

  p0_init<<<25, 256, 0, stream>>>(Vs, X0, Q0, ws);
  p_main<<<NBLK, 256, 0, stream>>>(Vs, ws);
  int total = Mv*3*Nv + 72 + 24 + Kv*3;
  p3_final<<<(total + 255)/256, 256, 0, stream>>>(Vs, ws, out);
}

// Round 7
// 220.326 us; speedup vs baseline: 3.1661x; 3.1661x over previous
//
#include <hip/hip_runtime.h>
#include <math.h>

#define Mv 8
#define Nv 8192
#define Kv 256
#define BPM 64            // blocks per m -> 512 blocks per iteration kernel
#define NBLK (Mv*BPM)
#define NITER 6
#define EPSILON_C 0.01f
#define GAMMA_C 0.005f

// ws layout (float offsets)
#define WS_R     0        // 72   (M x 3 x 3) -- initial identity (p0)
#define WS_T     72       // 24   (M x 3)     -- initial t0 (p0)
#define WS_X     96       // 768  (K x 3)     -- X0 (p0; never overwritten)
#define WS_Q     864      // 256  -- Q0
#define WS_BETA  1120     // 1
#define WS_ACC   1124     // 3 x ACCSZ triple-buffered accumulators
#define AC_STATS 0        // 128 (M x 16)
#define AC_L     128      // 2048 (M x K)
#define AC_W     2176     // 6144 (M x 3 x K)
#define AC_H     8320     // 2048 (M x K)
#define ACCSZ    10368

// ---- wave-wide sum via DPP; wave-uniform result. All lanes must be active.
__device__ __forceinline__ float wave_red_sum(float x) {
  int v;
  float t;
  v = __builtin_bit_cast(int, x);
  t = __builtin_bit_cast(float, __builtin_amdgcn_update_dpp(0, v, 0x111, 0xf, 0xf, true));  // row_shr:1
  x += t; v = __builtin_bit_cast(int, x);
  t = __builtin_bit_cast(float, __builtin_amdgcn_update_dpp(0, v, 0x112, 0xf, 0xf, true));  // row_shr:2
  x += t; v = __builtin_bit_cast(int, x);
  t = __builtin_bit_cast(float, __builtin_amdgcn_update_dpp(0, v, 0x114, 0xf, 0xf, true));  // row_shr:4
  x += t; v = __builtin_bit_cast(int, x);
  t = __builtin_bit_cast(float, __builtin_amdgcn_update_dpp(0, v, 0x118, 0xf, 0xf, true));  // row_shr:8
  x += t; v = __builtin_bit_cast(int, x);
  t = __builtin_bit_cast(float, __builtin_amdgcn_update_dpp(0, v, 0x142, 0xa, 0xf, false)); // row_bcast:15
  x += t; v = __builtin_bit_cast(int, x);
  t = __builtin_bit_cast(float, __builtin_amdgcn_update_dpp(0, v, 0x143, 0xc, 0xf, false)); // row_bcast:31
  x += t;
  return __builtin_bit_cast(float, __builtin_amdgcn_readlane(__builtin_bit_cast(int, x), 63));
}

// ---------------------------------------------------------------- init
__global__ __launch_bounds__(256) void p0_init(const float* __restrict__ Vs,
                                               const float* __restrict__ X0,
                                               const float* __restrict__ Q0,
                                               float* __restrict__ ws) {
  __shared__ float sred[4];
  int tid = threadIdx.x;
  int b = blockIdx.x;
  int wave = tid >> 6, lane = tid & 63;
  if (b < 24) {
    int m = b / 3, d = b % 3;
    const float* src = Vs + (size_t)(m*3 + d) * Nv;
    float s = 0.f;
    for (int n = tid; n < Nv; n += 256) s += src[n];
    s = wave_red_sum(s);
    if (lane == 0) sred[wave] = s;
    __syncthreads();
    if (tid == 0) {
      float tot = sred[0]+sred[1]+sred[2]+sred[3];
      ws[WS_T + m*3 + d] = -tot / (float)Nv;
    }
    if (d == 0 && tid < 9) {
      ws[WS_R + m*9 + tid] = (tid==0||tid==4||tid==8) ? 1.f : 0.f;
    }
  } else {
    float s = (tid < Kv) ? Q0[tid] : 0.f;
    s = wave_red_sum(s);
    if (lane == 0) sred[wave] = s;
    __syncthreads();
    if (tid == 0) {
      float mq = (sred[0]+sred[1]+sred[2]+sred[3]) / (float)Kv;
      ws[WS_BETA] = GAMMA_C * mq * sqrtf(mq);
    }
    if (tid < Kv) ws[WS_Q + tid] = Q0[tid];
    for (int i = tid; i < Kv*3; i += 256) ws[WS_X + i] = X0[i];
    // zero ACC buffer 0 (used by iteration 0); buffers 1,2 zeroed by K_0,K_1
    for (int i = tid; i < ACCSZ; i += 256) ws[WS_ACC + i] = 0.f;
  }
}

// ---- fp32 Jacobi rotation, COMPILE-TIME pair, named scalars only.
#define JROTF(app,aqq,apq,apr,aqr, vp0,vp1,vp2, vq0,vq1,vq2) do {           \
    float tau_ = (aqq - app) * __builtin_amdgcn_rcpf(2.0f*apq);             \
    float tt_ = __builtin_amdgcn_rcpf(fabsf(tau_) +                         \
                   __builtin_amdgcn_sqrtf(fmaf(tau_,tau_,1.0f)));           \
    tt_ = (tau_ < 0.0f) ? -tt_ : tt_;                                       \
    tt_ = (apq == 0.0f) ? 0.0f : tt_;                                       \
    float c_ = __builtin_amdgcn_rsqf(fmaf(tt_,tt_,1.0f)), s_ = tt_*c_;      \
    float papq_ = apq;                                                      \
    app = fmaf(-tt_,papq_,app); aqq = fmaf(tt_,papq_,aqq); apq = 0.0f;      \
    float tp_ = apr, tq_ = aqr;                                             \
    apr = c_*tp_ - s_*tq_; aqr = s_*tp_ + c_*tq_;                           \
    tp_=vp0; tq_=vq0; vp0=c_*tp_-s_*tq_; vq0=s_*tp_+c_*tq_;                 \
    tp_=vp1; tq_=vq1; vp1=c_*tp_-s_*tq_; vq1=s_*tp_+c_*tq_;                 \
    tp_=vp2; tq_=vq2; vp2=c_*tp_-s_*tq_; vq2=s_*tp_+c_*tq_;                 \
  } while(0)

#define CSWAP3F(la,lb, a0,a1,a2, b0,b1,b2) do {                             \
    if (la < lb) { float t_;                                                \
      t_=la; la=lb; lb=t_; t_=a0; a0=b0; b0=t_;                             \
      t_=a1; a1=b1; b1=t_; t_=a2; a2=b2; b2=t_; }                           \
  } while(0)

// ---- redundant small update: rebuild R/t (8-lane fp32 polar solve) and
// per-k X/Q for iteration `itprev` from acc. Runs identically in every block
// (same inputs -> bitwise-identical outputs). Contains one __syncthreads.
// Caller must __syncthreads() after before reading other threads' sX/sQ.
__device__ __forceinline__ void small_update(const float* __restrict__ acc,
                                             const float* __restrict__ ws,
                                             int itprev, int tid,
                                             float (*sX)[3], float* sQ,
                                             float (*sR)[9], float (*sT)[3],
                                             float* sTn) {
  const int k = tid;
  float lk[Mv], w0v[Mv], w1v[Mv], w2v[Mv], hk[Mv];
  #pragma unroll
  for (int mm=0;mm<Mv;mm++) {
    lk[mm]  = acc[AC_L + mm*Kv + k];
    w0v[mm] = acc[AC_W + (mm*3+0)*Kv + k];
    w1v[mm] = acc[AC_W + (mm*3+1)*Kv + k];
    w2v[mm] = acc[AC_W + (mm*3+2)*Kv + k];
    hk[mm]  = acc[AC_H + mm*Kv + k];
  }
  // X0 (only consumed when itprev <= 1; WS_X is never overwritten)
  float xp0 = ws[WS_X + k*3+0], xp1 = ws[WS_X + k*3+1], xp2 = ws[WS_X + k*3+2];

  if (tid < Mv) {
    int mm = tid;
    const float* st = acc + AC_STATS + mm*16;
    float s0=st[0], s1=st[1], s2v=st[2], s3=st[3], s4=st[4], s5=st[5],
          s6=st[6], s7=st[7], s8=st[8], s9=st[9], s10=st[10], s11=st[11],
          s12=st[12], s13=st[13], s14=st[14], s15=st[15];
    float z = s0;
    float mX0 = s1, mX1 = s2v, mX2 = s3;
    float mW0 = s4, mW1 = s5, mW2 = s6;
    float iz = 1.0f/z;
    float P00 = s7  - mX0*mW0*iz;
    float P01 = s8  - mX0*mW1*iz;
    float P02 = s9  - mX0*mW2*iz;
    float P10 = s10 - mX1*mW0*iz;
    float P11 = s11 - mX1*mW1*iz;
    float P12 = s12 - mX1*mW2*iz;
    float P20 = s13 - mX2*mW0*iz;
    float P21 = s14 - mX2*mW1*iz;
    float P22 = s15 - mX2*mW2*iz;
    float a00 = P00*P00 + P10*P10 + P20*P20;
    float a01 = P00*P01 + P10*P11 + P20*P21;
    float a02 = P00*P02 + P10*P12 + P20*P22;
    float a11 = P01*P01 + P11*P11 + P21*P21;
    float a12 = P01*P02 + P11*P12 + P21*P22;
    float a22 = P02*P02 + P12*P12 + P22*P22;
    float v00=1, v01=0, v02=0, v10=0, v11=1, v12=0, v20=0, v21=0, v22=1;
    #pragma unroll 1
    for (int sweep = 0; sweep < 8; sweep++) {
      JROTF(a00,a11,a01, a02,a12, v00,v10,v20, v01,v11,v21);
      JROTF(a00,a22,a02, a01,a12, v00,v10,v20, v02,v12,v22);
      JROTF(a11,a22,a12, a01,a02, v01,v11,v21, v02,v12,v22);
    }
    float l0 = a00, l1 = a11, l2 = a22;
    CSWAP3F(l0,l1, v00,v10,v20, v01,v11,v21);
    CSWAP3F(l1,l2, v01,v11,v21, v02,v12,v22);
    CSWAP3F(l0,l1, v00,v10,v20, v01,v11,v21);
    float detP = P00*(P11*P22-P12*P21) - P01*(P10*P22-P12*P20)
               + P02*(P10*P21-P11*P20);
    float s2d = (detP < 0.0f) ? -1.0f : 1.0f;
    float tiny = 1e-18f*l0 + 1e-30f;
    float w0i = __builtin_amdgcn_rsqf(fmaxf(l0,tiny));
    float w1i = __builtin_amdgcn_rsqf(fmaxf(l1,tiny));
    float w2i = s2d*__builtin_amdgcn_rsqf(fmaxf(l2,tiny));
    float M00 = w0i*v00*v00 + w1i*v01*v01 + w2i*v02*v02;
    float M01 = w0i*v00*v10 + w1i*v01*v11 + w2i*v02*v12;
    float M02 = w0i*v00*v20 + w1i*v01*v21 + w2i*v02*v22;
    float M11 = w0i*v10*v10 + w1i*v11*v11 + w2i*v12*v12;
    float M12 = w0i*v10*v20 + w1i*v11*v21 + w2i*v12*v22;
    float M22 = w0i*v20*v20 + w1i*v21*v21 + w2i*v22*v22;
    float R00n = P00*M00 + P01*M01 + P02*M02;
    float R01n = P00*M01 + P01*M11 + P02*M12;
    float R02n = P00*M02 + P01*M12 + P02*M22;
    float R10n = P10*M00 + P11*M01 + P12*M02;
    float R11n = P10*M01 + P11*M11 + P12*M12;
    float R12n = P10*M02 + P11*M12 + P12*M22;
    float R20n = P20*M00 + P21*M01 + P22*M02;
    float R21n = P20*M01 + P21*M11 + P22*M12;
    float R22n = P20*M02 + P21*M12 + P22*M22;
    float tm0 = (mX0 - (R00n*mW0 + R01n*mW1 + R02n*mW2))*iz;
    float tm1 = (mX1 - (R10n*mW0 + R11n*mW1 + R12n*mW2))*iz;
    float tm2 = (mX2 - (R20n*mW0 + R21n*mW1 + R22n*mW2))*iz;
    sR[mm][0]=R00n; sR[mm][1]=R01n; sR[mm][2]=R02n;
    sR[mm][3]=R10n; sR[mm][4]=R11n; sR[mm][5]=R12n;
    sR[mm][6]=R20n; sR[mm][7]=R21n; sR[mm][8]=R22n;
    sT[mm][0]=tm0; sT[mm][1]=tm1; sT[mm][2]=tm2;
    sTn[mm] = tm0*tm0 + tm1*tm1 + tm2*tm2;
  }
  __syncthreads();
  {
    float den = 0.f, Xn0=0.f, Xn1=0.f, Xn2=0.f, S2=0.f;
    #pragma unroll
    for (int mm=0;mm<Mv;mm++) {
      float r0 = sR[mm][0]*w0v[mm] + sR[mm][1]*w1v[mm] + sR[mm][2]*w2v[mm];
      float r1 = sR[mm][3]*w0v[mm] + sR[mm][4]*w1v[mm] + sR[mm][5]*w2v[mm];
      float r2 = sR[mm][6]*w0v[mm] + sR[mm][7]*w1v[mm] + sR[mm][8]*w2v[mm];
      float tt0 = sT[mm][0], tt1 = sT[mm][1], tt2 = sT[mm][2];
      den += lk[mm];
      Xn0 += r0 + tt0*lk[mm]; Xn1 += r1 + tt1*lk[mm]; Xn2 += r2 + tt2*lk[mm];
      S2  += hk[mm] + 2.f*(tt0*r0+tt1*r1+tt2*r2) + sTn[mm]*lk[mm];
    }
    float x0, x1, x2;
    if (itprev > 1) { float inv = 1.f/den; x0=Xn0*inv; x1=Xn1*inv; x2=Xn2*inv; }
    else            { x0=xp0; x1=xp1; x2=xp2; }
    float wn = S2 + (x0*x0+x1*x1+x2*x2)*den - 2.f*(x0*Xn0+x1*Xn1+x2*Xn2);
    float qn = 3.f*den / (wn + 3.f*den*EPSILON_C);
    sX[k][0]=x0; sX[k][1]=x1; sX[k][2]=x2;
    sQ[k] = qn;
  }
}

// ------------------------------------------- one-iteration kernel (512 blocks)
// Prologue: redundant small_update of iteration it-1 from acc[(it-1)%3]
// (dispatch boundary = sync + cross-XCD visibility; no grid barrier —
// R6 measured the software barrier at ~95us/iter, 3x the dispatch floor).
// Phase A: accumulate L/W/H + 16 per-m stats into acc[it%3] via atomics.
// Also partition-zeroes acc[(it+1)%3] (last read two dispatches ago).
__global__ __launch_bounds__(256) void p_iter(const float* __restrict__ Vs,
                                              float* __restrict__ ws, int it) {
  __shared__ float sb[4][5][Kv]; // 20 KB
  __shared__ float st4[4][16];
  __shared__ float sX[Kv][3];
  __shared__ float sQ[Kv];
  __shared__ float sR[Mv][9];
  __shared__ float sT[Mv][3];
  __shared__ float sTn[Mv];

  int tid  = threadIdx.x;
  int wave = tid >> 6, lane = tid & 63;
  int bid  = blockIdx.x;
  int m    = bid / BPM;
  int blk  = bid % BPM;
  int wid  = blk*4 + wave;
  const int k = tid;

  float* acc  = ws + WS_ACC + (it % 3)*ACCSZ;
  float* accz = ws + WS_ACC + ((it+1) % 3)*ACCSZ;
  float beta = ws[WS_BETA];

  if (it == 0) {
    if (tid < 72) ((float*)sR)[tid] = ws[WS_R + tid];
    if (tid < 24) ((float*)sT)[tid] = ws[WS_T + tid];
    sX[k][0] = ws[WS_X + 3*k+0];
    sX[k][1] = ws[WS_X + 3*k+1];
    sX[k][2] = ws[WS_X + 3*k+2];
    sQ[k]    = ws[WS_Q + k];
  } else {
    const float* accp = ws + WS_ACC + ((it+2) % 3)*ACCSZ;  // (it-1)%3
    small_update(accp, ws, it-1, tid, sX, sQ, sR, sT, sTn);
  }
  __syncthreads();

  // partitioned zero of buffer (it+1)%3
  { int base = bid*21;
    if (tid < 21 && base + tid < ACCSZ) accz[base + tid] = 0.f; }

  // ---- phase A
  float R00=sR[m][0],R01=sR[m][1],R02=sR[m][2];
  float R10=sR[m][3],R11=sR[m][4],R12=sR[m][5];
  float R20=sR[m][6],R21=sR[m][7],R22=sR[m][8];
  float t0=sT[m][0], t1=sT[m][1], t2=sT[m][2];
  float kXx[4],kXy[4],kXz[4],kA[4],kB[4],kQ[4],kQ32[4];
  #pragma unroll
  for (int j=0;j<4;j++) {
    int kk = lane + 64*j;
    float xx = sX[kk][0], xy = sX[kk][1], xz = sX[kk][2];
    float q  = sQ[kk];
    kXx[j]=xx; kXy[j]=xy; kXz[j]=xz;
    kA[j]  = -0.5f*q;
    kB[j]  = kA[j]*(xx*xx+xy*xy+xz*xz);
    kQ[j]  = q;
    kQ32[j]= q*sqrtf(q);
  }
  float aL[4]={0,0,0,0}, aWx[4]={0,0,0,0}, aWy[4]={0,0,0,0},
        aWz[4]={0,0,0,0}, aH[4]={0,0,0,0};
  const float* V0 = Vs + (size_t)(m*3+0)*Nv;
  const float* V1 = Vs + (size_t)(m*3+1)*Nv;
  const float* V2 = Vs + (size_t)(m*3+2)*Nv;
  for (int n = wid; n < Nv; n += 256) {
    float vx = V0[n], vy = V1[n], vz = V2[n];
    float px = fmaf(R00,vx, fmaf(R01,vy, fmaf(R02,vz, t0)));
    float py = fmaf(R10,vx, fmaf(R11,vy, fmaf(R12,vz, t1)));
    float pz = fmaf(R20,vx, fmaf(R21,vy, fmaf(R22,vz, t2)));
    float tvn = fmaf(px,px, fmaf(py,py, pz*pz));
    float vn  = fmaf(vx,vx, fmaf(vy,vy, vz*vz));
    float ap[4]; float s = 0.f;
    #pragma unroll
    for (int j=0;j<4;j++) {
      float dot = fmaf(px,kXx[j], fmaf(py,kXy[j], pz*kXz[j]));
      float arg = fmaf(kQ[j], dot, fmaf(kA[j], tvn, kB[j]));
      float e = __expf(arg)*kQ32[j];
      ap[j] = e; s += e;
    }
    float S = wave_red_sum(s);
    float inv = 1.f/(S + beta);
    #pragma unroll
    for (int j=0;j<4;j++) {
      float a = ap[j]*inv;
      aL[j] += a;
      aWx[j] = fmaf(a,vx,aWx[j]);
      aWy[j] = fmaf(a,vy,aWy[j]);
      aWz[j] = fmaf(a,vz,aWz[j]);
      aH[j]  = fmaf(a,vn,aH[j]);
    }
  }
  #pragma unroll
  for (int j=0;j<4;j++) {
    int kk = lane + 64*j;
    sb[wave][0][kk]=aL[j];  sb[wave][1][kk]=aWx[j]; sb[wave][2][kk]=aWy[j];
    sb[wave][3][kk]=aWz[j]; sb[wave][4][kk]=aH[j];
  }
  __syncthreads();
  float vL  = sb[0][0][k]+sb[1][0][k]+sb[2][0][k]+sb[3][0][k];
  float vWx = sb[0][1][k]+sb[1][1][k]+sb[2][1][k]+sb[3][1][k];
  float vWy = sb[0][2][k]+sb[1][2][k]+sb[2][2][k]+sb[3][2][k];
  float vWz = sb[0][3][k]+sb[1][3][k]+sb[2][3][k]+sb[3][3][k];
  float vH  = sb[0][4][k]+sb[1][4][k]+sb[2][4][k]+sb[3][4][k];
  atomicAdd(&acc[AC_L + m*Kv + k], vL);
  atomicAdd(&acc[AC_W + (m*3+0)*Kv + k], vWx);
  atomicAdd(&acc[AC_W + (m*3+1)*Kv + k], vWy);
  atomicAdd(&acc[AC_W + (m*3+2)*Kv + k], vWz);
  atomicAdd(&acc[AC_H + m*Kv + k], vH);
  {
    float q  = sQ[k];
    float x0 = sX[k][0], x1 = sX[k][1], x2 = sX[k][2];
    float bk = vL*q;
    float sw0 = vWx*q, sw1 = vWy*q, sw2 = vWz*q;
    float pr[16];
    pr[0]=bk;  pr[1]=bk*x0; pr[2]=bk*x1; pr[3]=bk*x2;
    pr[4]=sw0; pr[5]=sw1;   pr[6]=sw2;
    pr[7]=sw0*x0;  pr[8]=sw1*x0;  pr[9]=sw2*x0;
    pr[10]=sw0*x1; pr[11]=sw1*x1; pr[12]=sw2*x1;
    pr[13]=sw0*x2; pr[14]=sw1*x2; pr[15]=sw2*x2;
    float red[16];
    #pragma unroll
    for (int v2=0; v2<16; v2++) red[v2] = wave_red_sum(pr[v2]);
    if (lane == 0) {
      #pragma unroll
      for (int v2=0; v2<16; v2++) st4[wave][v2] = red[v2];
    }
    __syncthreads();
    if (k < 16)
      atomicAdd(&acc[AC_STATS + m*16 + k],
                st4[0][k]+st4[1][k]+st4[2][k]+st4[3][k]);
  }
}

// ------------------------------- final: prologue finalizes iter 5, then write
__global__ __launch_bounds__(256) void p3_final(const float* __restrict__ Vs,
                                                const float* __restrict__ ws,
                                                float* __restrict__ out) {
  __shared__ float sX[Kv][3];
  __shared__ float sQ[Kv];
  __shared__ float sR[Mv][9];
  __shared__ float sT[Mv][3];
  __shared__ float sTn[Mv];
  int tid = threadIdx.x;
  const float* acc = ws + WS_ACC + ((NITER-1) % 3)*ACCSZ;
  small_update(acc, ws, NITER-1, tid, sX, sQ, sR, sT, sTn);
  __syncthreads();

  int idx = blockIdx.x*256 + tid;
  if (idx < Mv*3*Nv) {
    int m = idx / (3*Nv);
    int r = idx % (3*Nv);
    int d = r / Nv;
    int n = r % Nv;
    float vx = Vs[(size_t)(m*3+0)*Nv + n];
    float vy = Vs[(size_t)(m*3+1)*Nv + n];
    float vz = Vs[(size_t)(m*3+2)*Nv + n];
    out[idx] = fmaf(sR[m][d*3+0],vx,
               fmaf(sR[m][d*3+1],vy,
               fmaf(sR[m][d*3+2],vz, sT[m][d])));
  } else if (idx < Mv*3*Nv + 72 + 24 + Kv*3) {
    int j = idx - Mv*3*Nv;
    float v;
    if (j < 72)      v = ((float*)sR)[j];
    else if (j < 96) v = ((float*)sT)[j-72];
    else             v = ((float*)sX)[j-96];
    out[idx] = v;
  }
}

extern "C" void kernel_launch(void* const* d_in, const int* in_sizes, int n_in,
                              void* d_out, int out_size, void* d_ws, size_t ws_size,
                              hipStream_t stream) {
  const float* Vs = (const float*)d_in[0];
  const float* X0 = (const float*)d_in[1];
  const float* Q0 = (const float*)d_in[2];
  float* out = (float*)d_out;
  float* ws  = (float*)d_ws;

  p0_init<<<25, 256, 0, stream>>>(Vs, X0, Q0, ws);
  for (int i = 0; i < NITER; i++)
    p_iter<<<NBLK, 256, 0, stream>>>(Vs, ws, i);
  int total = Mv*3*Nv + 72 + 24 + Kv*3;
  p3_final<<<(total + 255)/256, 256, 0, stream>>>(Vs, ws, out);
}

// Round 8
// 214.589 us; speedup vs baseline: 3.2507x; 1.0267x over previous
//
#include <hip/hip_runtime.h>
#include <math.h>

#define Mv 8
#define Nv 8192
#define Kv 256
#define BPM 64            // blocks per m -> 512 blocks per iteration kernel
#define NBLK (Mv*BPM)
#define NITER 6
#define EPSILON_C 0.01f
#define GAMMA_C 0.005f

// ws layout (float offsets)
#define WS_R     0        // 72   (M x 3 x 3) -- initial identity (p0)
#define WS_T     72       // 24   (M x 3)     -- initial t0 (p0)
#define WS_X     96       // 768  (K x 3)     -- X0 (p0; never overwritten)
#define WS_Q     864      // 256  -- Q0
#define WS_BETA  1120     // 1
#define WS_ACC   1124     // 3 x ACCSZ triple-buffered accumulators
#define AC_STATS 0        // 128 (M x 16)
#define AC_L     128      // 2048 (M x K)
#define AC_W     2176     // 6144 (M x 3 x K)
#define AC_H     8320     // 2048 (M x K)
#define ACCSZ    10368

// ---- wave-wide sum via DPP; wave-uniform result. All lanes must be active.
__device__ __forceinline__ float wave_red_sum(float x) {
  int v;
  float t;
  v = __builtin_bit_cast(int, x);
  t = __builtin_bit_cast(float, __builtin_amdgcn_update_dpp(0, v, 0x111, 0xf, 0xf, true));  // row_shr:1
  x += t; v = __builtin_bit_cast(int, x);
  t = __builtin_bit_cast(float, __builtin_amdgcn_update_dpp(0, v, 0x112, 0xf, 0xf, true));  // row_shr:2
  x += t; v = __builtin_bit_cast(int, x);
  t = __builtin_bit_cast(float, __builtin_amdgcn_update_dpp(0, v, 0x114, 0xf, 0xf, true));  // row_shr:4
  x += t; v = __builtin_bit_cast(int, x);
  t = __builtin_bit_cast(float, __builtin_amdgcn_update_dpp(0, v, 0x118, 0xf, 0xf, true));  // row_shr:8
  x += t; v = __builtin_bit_cast(int, x);
  t = __builtin_bit_cast(float, __builtin_amdgcn_update_dpp(0, v, 0x142, 0xa, 0xf, false)); // row_bcast:15
  x += t; v = __builtin_bit_cast(int, x);
  t = __builtin_bit_cast(float, __builtin_amdgcn_update_dpp(0, v, 0x143, 0xc, 0xf, false)); // row_bcast:31
  x += t;
  return __builtin_bit_cast(float, __builtin_amdgcn_readlane(__builtin_bit_cast(int, x), 63));
}

// ---------------------------------------------------------------- init
__global__ __launch_bounds__(256) void p0_init(const float* __restrict__ Vs,
                                               const float* __restrict__ X0,
                                               const float* __restrict__ Q0,
                                               float* __restrict__ ws) {
  __shared__ float sred[4];
  int tid = threadIdx.x;
  int b = blockIdx.x;
  int wave = tid >> 6, lane = tid & 63;
  if (b < 24) {
    int m = b / 3, d = b % 3;
    const float* src = Vs + (size_t)(m*3 + d) * Nv;
    float s = 0.f;
    for (int n = tid; n < Nv; n += 256) s += src[n];
    s = wave_red_sum(s);
    if (lane == 0) sred[wave] = s;
    __syncthreads();
    if (tid == 0) {
      float tot = sred[0]+sred[1]+sred[2]+sred[3];
      ws[WS_T + m*3 + d] = -tot / (float)Nv;
    }
    if (d == 0 && tid < 9) {
      ws[WS_R + m*9 + tid] = (tid==0||tid==4||tid==8) ? 1.f : 0.f;
    }
  } else {
    float s = (tid < Kv) ? Q0[tid] : 0.f;
    s = wave_red_sum(s);
    if (lane == 0) sred[wave] = s;
    __syncthreads();
    if (tid == 0) {
      float mq = (sred[0]+sred[1]+sred[2]+sred[3]) / (float)Kv;
      ws[WS_BETA] = GAMMA_C * mq * sqrtf(mq);
    }
    if (tid < Kv) ws[WS_Q + tid] = Q0[tid];
    for (int i = tid; i < Kv*3; i += 256) ws[WS_X + i] = X0[i];
    for (int i = tid; i < ACCSZ; i += 256) ws[WS_ACC + i] = 0.f;
  }
}

// ---- fp32 Jacobi rotation, COMPILE-TIME pair, named scalars only.
#define JROTF(app,aqq,apq,apr,aqr, vp0,vp1,vp2, vq0,vq1,vq2) do {           \
    float tau_ = (aqq - app) * __builtin_amdgcn_rcpf(2.0f*apq);             \
    float tt_ = __builtin_amdgcn_rcpf(fabsf(tau_) +                         \
                   __builtin_amdgcn_sqrtf(fmaf(tau_,tau_,1.0f)));           \
    tt_ = (tau_ < 0.0f) ? -tt_ : tt_;                                       \
    tt_ = (apq == 0.0f) ? 0.0f : tt_;                                       \
    float c_ = __builtin_amdgcn_rsqf(fmaf(tt_,tt_,1.0f)), s_ = tt_*c_;      \
    float papq_ = apq;                                                      \
    app = fmaf(-tt_,papq_,app); aqq = fmaf(tt_,papq_,aqq); apq = 0.0f;      \
    float tp_ = apr, tq_ = aqr;                                             \
    apr = c_*tp_ - s_*tq_; aqr = s_*tp_ + c_*tq_;                           \
    tp_=vp0; tq_=vq0; vp0=c_*tp_-s_*tq_; vq0=s_*tp_+c_*tq_;                 \
    tp_=vp1; tq_=vq1; vp1=c_*tp_-s_*tq_; vq1=s_*tp_+c_*tq_;                 \
    tp_=vp2; tq_=vq2; vp2=c_*tp_-s_*tq_; vq2=s_*tp_+c_*tq_;                 \
  } while(0)

#define CSWAP3F(la,lb, a0,a1,a2, b0,b1,b2) do {                             \
    if (la < lb) { float t_;                                                \
      t_=la; la=lb; lb=t_; t_=a0; a0=b0; b0=t_;                             \
      t_=a1; a1=b1; b1=t_; t_=a2; a2=b2; b2=t_; }                           \
  } while(0)

// ---- redundant small update for iteration `itprev` from acc -> sX/sQ/sR/sT.
// Runs identically in every block. Contains one internal __syncthreads;
// caller must __syncthreads() after before reading other threads' sX/sQ.
__device__ __forceinline__ void small_update(const float* __restrict__ acc,
                                             const float* __restrict__ ws,
                                             int itprev, int tid,
                                             float (*sX)[3], float* sQ,
                                             float (*sR)[9], float (*sT)[3],
                                             float* sTn) {
  const int k = tid;
  float lk[Mv], w0v[Mv], w1v[Mv], w2v[Mv], hk[Mv];
  #pragma unroll
  for (int mm=0;mm<Mv;mm++) {
    lk[mm]  = acc[AC_L + mm*Kv + k];
    w0v[mm] = acc[AC_W + (mm*3+0)*Kv + k];
    w1v[mm] = acc[AC_W + (mm*3+1)*Kv + k];
    w2v[mm] = acc[AC_W + (mm*3+2)*Kv + k];
    hk[mm]  = acc[AC_H + mm*Kv + k];
  }
  float xp0 = ws[WS_X + k*3+0], xp1 = ws[WS_X + k*3+1], xp2 = ws[WS_X + k*3+2];

  if (tid < Mv) {
    int mm = tid;
    const float* st = acc + AC_STATS + mm*16;
    float s0=st[0], s1=st[1], s2v=st[2], s3=st[3], s4=st[4], s5=st[5],
          s6=st[6], s7=st[7], s8=st[8], s9=st[9], s10=st[10], s11=st[11],
          s12=st[12], s13=st[13], s14=st[14], s15=st[15];
    float z = s0;
    float mX0 = s1, mX1 = s2v, mX2 = s3;
    float mW0 = s4, mW1 = s5, mW2 = s6;
    float iz = __builtin_amdgcn_rcpf(z);
    float P00 = s7  - mX0*mW0*iz;
    float P01 = s8  - mX0*mW1*iz;
    float P02 = s9  - mX0*mW2*iz;
    float P10 = s10 - mX1*mW0*iz;
    float P11 = s11 - mX1*mW1*iz;
    float P12 = s12 - mX1*mW2*iz;
    float P20 = s13 - mX2*mW0*iz;
    float P21 = s14 - mX2*mW1*iz;
    float P22 = s15 - mX2*mW2*iz;
    float a00 = P00*P00 + P10*P10 + P20*P20;
    float a01 = P00*P01 + P10*P11 + P20*P21;
    float a02 = P00*P02 + P10*P12 + P20*P22;
    float a11 = P01*P01 + P11*P11 + P21*P21;
    float a12 = P01*P02 + P11*P12 + P21*P22;
    float a22 = P02*P02 + P12*P12 + P22*P22;
    float v00=1, v01=0, v02=0, v10=0, v11=1, v12=0, v20=0, v21=0, v22=1;
    #pragma unroll 1
    for (int sweep = 0; sweep < 8; sweep++) {
      JROTF(a00,a11,a01, a02,a12, v00,v10,v20, v01,v11,v21);
      JROTF(a00,a22,a02, a01,a12, v00,v10,v20, v02,v12,v22);
      JROTF(a11,a22,a12, a01,a02, v01,v11,v21, v02,v12,v22);
    }
    float l0 = a00, l1 = a11, l2 = a22;
    CSWAP3F(l0,l1, v00,v10,v20, v01,v11,v21);
    CSWAP3F(l1,l2, v01,v11,v21, v02,v12,v22);
    CSWAP3F(l0,l1, v00,v10,v20, v01,v11,v21);
    float detP = P00*(P11*P22-P12*P21) - P01*(P10*P22-P12*P20)
               + P02*(P10*P21-P11*P20);
    float s2d = (detP < 0.0f) ? -1.0f : 1.0f;
    float tiny = 1e-18f*l0 + 1e-30f;
    float w0i = __builtin_amdgcn_rsqf(fmaxf(l0,tiny));
    float w1i = __builtin_amdgcn_rsqf(fmaxf(l1,tiny));
    float w2i = s2d*__builtin_amdgcn_rsqf(fmaxf(l2,tiny));
    float M00 = w0i*v00*v00 + w1i*v01*v01 + w2i*v02*v02;
    float M01 = w0i*v00*v10 + w1i*v01*v11 + w2i*v02*v12;
    float M02 = w0i*v00*v20 + w1i*v01*v21 + w2i*v02*v22;
    float M11 = w0i*v10*v10 + w1i*v11*v11 + w2i*v12*v12;
    float M12 = w0i*v10*v20 + w1i*v11*v21 + w2i*v12*v22;
    float M22 = w0i*v20*v20 + w1i*v21*v21 + w2i*v22*v22;
    float R00n = P00*M00 + P01*M01 + P02*M02;
    float R01n = P00*M01 + P01*M11 + P02*M12;
    float R02n = P00*M02 + P01*M12 + P02*M22;
    float R10n = P10*M00 + P11*M01 + P12*M02;
    float R11n = P10*M01 + P11*M11 + P12*M12;
    float R12n = P10*M02 + P11*M12 + P12*M22;
    float R20n = P20*M00 + P21*M01 + P22*M02;
    float R21n = P20*M01 + P21*M11 + P22*M12;
    float R22n = P20*M02 + P21*M12 + P22*M22;
    float tm0 = (mX0 - (R00n*mW0 + R01n*mW1 + R02n*mW2))*iz;
    float tm1 = (mX1 - (R10n*mW0 + R11n*mW1 + R12n*mW2))*iz;
    float tm2 = (mX2 - (R20n*mW0 + R21n*mW1 + R22n*mW2))*iz;
    sR[mm][0]=R00n; sR[mm][1]=R01n; sR[mm][2]=R02n;
    sR[mm][3]=R10n; sR[mm][4]=R11n; sR[mm][5]=R12n;
    sR[mm][6]=R20n; sR[mm][7]=R21n; sR[mm][8]=R22n;
    sT[mm][0]=tm0; sT[mm][1]=tm1; sT[mm][2]=tm2;
    sTn[mm] = tm0*tm0 + tm1*tm1 + tm2*tm2;
  }
  __syncthreads();
  {
    float den = 0.f, Xn0=0.f, Xn1=0.f, Xn2=0.f, S2=0.f;
    #pragma unroll
    for (int mm=0;mm<Mv;mm++) {
      float r0 = sR[mm][0]*w0v[mm] + sR[mm][1]*w1v[mm] + sR[mm][2]*w2v[mm];
      float r1 = sR[mm][3]*w0v[mm] + sR[mm][4]*w1v[mm] + sR[mm][5]*w2v[mm];
      float r2 = sR[mm][6]*w0v[mm] + sR[mm][7]*w1v[mm] + sR[mm][8]*w2v[mm];
      float tt0 = sT[mm][0], tt1 = sT[mm][1], tt2 = sT[mm][2];
      den += lk[mm];
      Xn0 += r0 + tt0*lk[mm]; Xn1 += r1 + tt1*lk[mm]; Xn2 += r2 + tt2*lk[mm];
      S2  += hk[mm] + 2.f*(tt0*r0+tt1*r1+tt2*r2) + sTn[mm]*lk[mm];
    }
    float x0, x1, x2;
    if (itprev > 1) { float inv = __builtin_amdgcn_rcpf(den);
                      x0=Xn0*inv; x1=Xn1*inv; x2=Xn2*inv; }
    else            { x0=xp0; x1=xp1; x2=xp2; }
    float wn = S2 + (x0*x0+x1*x1+x2*x2)*den - 2.f*(x0*Xn0+x1*Xn1+x2*Xn2);
    float qn = 3.f*den / (wn + 3.f*den*EPSILON_C);
    sX[k][0]=x0; sX[k][1]=x1; sX[k][2]=x2;
    sQ[k] = qn;
  }
}

// ------------------------------------------- one-iteration kernel (512 blocks)
// Prologue: redundant small_update of it-1 (dispatch boundary = sync).
// Phase A: accumulate into acc[it%3] via atomics. Atomic targets are block-
// permuted (k2 = tid + 4*blk) to break 64-deep same-address contention —
// R7's ~20us/iter unexplained stall is attributed to far-atomic serialization
// (R6's WRITE_SIZE showed atomics land in HBM).
__global__ __launch_bounds__(256) void p_iter(const float* __restrict__ Vs,
                                              float* __restrict__ ws, int it) {
  __shared__ float sb[4][5][Kv]; // 20 KB
  __shared__ float st4[4][16];
  __shared__ float sX[Kv][3];
  __shared__ float sQ[Kv];
  __shared__ float sR[Mv][9];
  __shared__ float sT[Mv][3];
  __shared__ float sTn[Mv];

  int tid  = threadIdx.x;
  int wave = tid >> 6, lane = tid & 63;
  int bid  = blockIdx.x;
  int m    = bid / BPM;
  int blk  = bid % BPM;
  int wid  = blk*4 + wave;
  const int k = tid;

  float* acc  = ws + WS_ACC + (it % 3)*ACCSZ;
  float* accz = ws + WS_ACC + ((it+1) % 3)*ACCSZ;
  float beta = ws[WS_BETA];

  if (it == 0) {
    if (tid < 72) ((float*)sR)[tid] = ws[WS_R + tid];
    if (tid < 24) ((float*)sT)[tid] = ws[WS_T + tid];
    sX[k][0] = ws[WS_X + 3*k+0];
    sX[k][1] = ws[WS_X + 3*k+1];
    sX[k][2] = ws[WS_X + 3*k+2];
    sQ[k]    = ws[WS_Q + k];
  } else {
    const float* accp = ws + WS_ACC + ((it+2) % 3)*ACCSZ;  // (it-1)%3
    small_update(accp, ws, it-1, tid, sX, sQ, sR, sT, sTn);
  }
  __syncthreads();

  // partitioned zero of buffer (it+1)%3
  { int base = bid*21;
    if (tid < 21 && base + tid < ACCSZ) accz[base + tid] = 0.f; }

  // ---- phase A
  float R00=sR[m][0],R01=sR[m][1],R02=sR[m][2];
  float R10=sR[m][3],R11=sR[m][4],R12=sR[m][5];
  float R20=sR[m][6],R21=sR[m][7],R22=sR[m][8];
  float t0=sT[m][0], t1=sT[m][1], t2=sT[m][2];
  float kXx[4],kXy[4],kXz[4],kA[4],kB[4],kQ[4],kQ32[4];
  #pragma unroll
  for (int j=0;j<4;j++) {
    int kk = lane + 64*j;
    float xx = sX[kk][0], xy = sX[kk][1], xz = sX[kk][2];
    float q  = sQ[kk];
    kXx[j]=xx; kXy[j]=xy; kXz[j]=xz;
    kA[j]  = -0.5f*q;
    kB[j]  = kA[j]*(xx*xx+xy*xy+xz*xz);
    kQ[j]  = q;
    kQ32[j]= q*sqrtf(q);
  }
  float aL[4]={0,0,0,0}, aWx[4]={0,0,0,0}, aWy[4]={0,0,0,0},
        aWz[4]={0,0,0,0}, aH[4]={0,0,0,0};
  const float* V0 = Vs + (size_t)(m*3+0)*Nv;
  const float* V1 = Vs + (size_t)(m*3+1)*Nv;
  const float* V2 = Vs + (size_t)(m*3+2)*Nv;
  for (int n = wid; n < Nv; n += 256) {
    float vx = V0[n], vy = V1[n], vz = V2[n];
    float px = fmaf(R00,vx, fmaf(R01,vy, fmaf(R02,vz, t0)));
    float py = fmaf(R10,vx, fmaf(R11,vy, fmaf(R12,vz, t1)));
    float pz = fmaf(R20,vx, fmaf(R21,vy, fmaf(R22,vz, t2)));
    float tvn = fmaf(px,px, fmaf(py,py, pz*pz));
    float vn  = fmaf(vx,vx, fmaf(vy,vy, vz*vz));
    float ap[4]; float s = 0.f;
    #pragma unroll
    for (int j=0;j<4;j++) {
      float dot = fmaf(px,kXx[j], fmaf(py,kXy[j], pz*kXz[j]));
      float arg = fmaf(kQ[j], dot, fmaf(kA[j], tvn, kB[j]));
      float e = __expf(arg)*kQ32[j];
      ap[j] = e; s += e;
    }
    float S = wave_red_sum(s);
    float inv = __builtin_amdgcn_rcpf(S + beta);
    #pragma unroll
    for (int j=0;j<4;j++) {
      float a = ap[j]*inv;
      aL[j] += a;
      aWx[j] = fmaf(a,vx,aWx[j]);
      aWy[j] = fmaf(a,vy,aWy[j]);
      aWz[j] = fmaf(a,vz,aWz[j]);
      aH[j]  = fmaf(a,vn,aH[j]);
    }
  }
  #pragma unroll
  for (int j=0;j<4;j++) {
    int kk = lane + 64*j;
    sb[wave][0][kk]=aL[j];  sb[wave][1][kk]=aWx[j]; sb[wave][2][kk]=aWy[j];
    sb[wave][3][kk]=aWz[j]; sb[wave][4][kk]=aH[j];
  }
  __syncthreads();
  // block-permuted column: breaks cross-block same-address atomic pile-up
  const int k2 = (tid + 4*blk) & (Kv-1);
  float vL  = sb[0][0][k2]+sb[1][0][k2]+sb[2][0][k2]+sb[3][0][k2];
  float vWx = sb[0][1][k2]+sb[1][1][k2]+sb[2][1][k2]+sb[3][1][k2];
  float vWy = sb[0][2][k2]+sb[1][2][k2]+sb[2][2][k2]+sb[3][2][k2];
  float vWz = sb[0][3][k2]+sb[1][3][k2]+sb[2][3][k2]+sb[3][3][k2];
  float vH  = sb[0][4][k2]+sb[1][4][k2]+sb[2][4][k2]+sb[3][4][k2];
  atomicAdd(&acc[AC_L + m*Kv + k2], vL);
  atomicAdd(&acc[AC_W + (m*3+0)*Kv + k2], vWx);
  atomicAdd(&acc[AC_W + (m*3+1)*Kv + k2], vWy);
  atomicAdd(&acc[AC_W + (m*3+2)*Kv + k2], vWz);
  atomicAdd(&acc[AC_H + m*Kv + k2], vH);
  {
    float q  = sQ[k2];
    float x0 = sX[k2][0], x1 = sX[k2][1], x2 = sX[k2][2];
    float bk = vL*q;
    float sw0 = vWx*q, sw1 = vWy*q, sw2 = vWz*q;
    float pr[16];
    pr[0]=bk;  pr[1]=bk*x0; pr[2]=bk*x1; pr[3]=bk*x2;
    pr[4]=sw0; pr[5]=sw1;   pr[6]=sw2;
    pr[7]=sw0*x0;  pr[8]=sw1*x0;  pr[9]=sw2*x0;
    pr[10]=sw0*x1; pr[11]=sw1*x1; pr[12]=sw2*x1;
    pr[13]=sw0*x2; pr[14]=sw1*x2; pr[15]=sw2*x2;
    float red[16];
    #pragma unroll
    for (int v2=0; v2<16; v2++) red[v2] = wave_red_sum(pr[v2]);
    if (lane == 0) {
      #pragma unroll
      for (int v2=0; v2<16; v2++) st4[wave][v2] = red[v2];
    }
    __syncthreads();
    if (tid < 16)
      atomicAdd(&acc[AC_STATS + m*16 + ((tid + blk) & 15)],
                st4[0][(tid+blk)&15]+st4[1][(tid+blk)&15]+
                st4[2][(tid+blk)&15]+st4[3][(tid+blk)&15]);
  }
}

// ------------------------------- final: prologue finalizes iter 5, then write
// 256 blocks + grid-stride (3x less redundant prologue HBM traffic than 769).
#define OUT_TOTAL (Mv*3*Nv + 72 + 24 + Kv*3)
__global__ __launch_bounds__(256) void p3_final(const float* __restrict__ Vs,
                                                const float* __restrict__ ws,
                                                float* __restrict__ out) {
  __shared__ float sX[Kv][3];
  __shared__ float sQ[Kv];
  __shared__ float sR[Mv][9];
  __shared__ float sT[Mv][3];
  __shared__ float sTn[Mv];
  int tid = threadIdx.x;
  const float* acc = ws + WS_ACC + ((NITER-1) % 3)*ACCSZ;
  small_update(acc, ws, NITER-1, tid, sX, sQ, sR, sT, sTn);
  __syncthreads();

  for (int idx = blockIdx.x*256 + tid; idx < OUT_TOTAL; idx += 256*256) {
    if (idx < Mv*3*Nv) {
      int m = idx / (3*Nv);
      int r = idx % (3*Nv);
      int d = r / Nv;
      int n = r % Nv;
      float vx = Vs[(size_t)(m*3+0)*Nv + n];
      float vy = Vs[(size_t)(m*3+1)*Nv + n];
      float vz = Vs[(size_t)(m*3+2)*Nv + n];
      out[idx] = fmaf(sR[m][d*3+0],vx,
                 fmaf(sR[m][d*3+1],vy,
                 fmaf(sR[m][d*3+2],vz, sT[m][d])));
    } else {
      int j = idx - Mv*3*Nv;
      float v;
      if (j < 72)      v = ((float*)sR)[j];
      else if (j < 96) v = ((float*)sT)[j-72];
      else             v = ((float*)sX)[j-96];
      out[idx] = v;
    }
  }
}

extern "C" void kernel_launch(void* const* d_in, const int* in_sizes, int n_in,
                              void* d_out, int out_size, void* d_ws, size_t ws_size,
                              hipStream_t stream) {
  const float* Vs = (const float*)d_in[0];
  const float* X0 = (const float*)d_in[1];
  const float* Q0 = (const float*)d_in[2];
  float* out = (float*)d_out;
  float* ws  = (float*)d_ws;

  p0_init<<<25, 256, 0, stream>>>(Vs, X0, Q0, ws);
  for (int i = 0; i < NITER; i++)
    p_iter<<<NBLK, 256, 0, stream>>>(Vs, ws, i);
  p3_final<<<256, 256, 0, stream>>>(Vs, ws, out);
}

// Round 9
// 213.185 us; speedup vs baseline: 3.2721x; 1.0066x over previous
//
#include <hip/hip_runtime.h>
#include <math.h>

#define Mv 8
#define Nv 8192
#define Kv 256
#define BPM 64            // blocks per m -> 512 blocks per iteration kernel
#define NBLK (Mv*BPM)
#define NITER 6
#define EPSILON_C 0.01f
#define GAMMA_C 0.005f

// ws layout (float offsets)
#define WS_R     0        // 72   (M x 3 x 3) -- initial identity (p0)
#define WS_T     72       // 24   (M x 3)     -- initial t0 (p0)
#define WS_X     96       // 768  (K x 3)     -- X0 (p0; never overwritten)
#define WS_Q     864      // 256  -- Q0
#define WS_BETA  1120     // 1
#define WS_ACC   1124     // 3 x ACCSZ triple-buffered accumulators
#define AC_STATS 0        // 128 (M x 16)
#define AC_L     128      // 2048 (M x K)
#define AC_W     2176     // 6144 (M x 3 x K)
#define AC_H     8320     // 2048 (M x K)
#define ACCSZ    10368

// ---- wave-wide sum via DPP; wave-uniform result. All lanes must be active.
__device__ __forceinline__ float wave_red_sum(float x) {
  int v;
  float t;
  v = __builtin_bit_cast(int, x);
  t = __builtin_bit_cast(float, __builtin_amdgcn_update_dpp(0, v, 0x111, 0xf, 0xf, true));  // row_shr:1
  x += t; v = __builtin_bit_cast(int, x);
  t = __builtin_bit_cast(float, __builtin_amdgcn_update_dpp(0, v, 0x112, 0xf, 0xf, true));  // row_shr:2
  x += t; v = __builtin_bit_cast(int, x);
  t = __builtin_bit_cast(float, __builtin_amdgcn_update_dpp(0, v, 0x114, 0xf, 0xf, true));  // row_shr:4
  x += t; v = __builtin_bit_cast(int, x);
  t = __builtin_bit_cast(float, __builtin_amdgcn_update_dpp(0, v, 0x118, 0xf, 0xf, true));  // row_shr:8
  x += t; v = __builtin_bit_cast(int, x);
  t = __builtin_bit_cast(float, __builtin_amdgcn_update_dpp(0, v, 0x142, 0xa, 0xf, false)); // row_bcast:15
  x += t; v = __builtin_bit_cast(int, x);
  t = __builtin_bit_cast(float, __builtin_amdgcn_update_dpp(0, v, 0x143, 0xc, 0xf, false)); // row_bcast:31
  x += t;
  return __builtin_bit_cast(float, __builtin_amdgcn_readlane(__builtin_bit_cast(int, x), 63));
}

// ---------------------------------------------------------------- init
__global__ __launch_bounds__(256) void p0_init(const float* __restrict__ Vs,
                                               const float* __restrict__ X0,
                                               const float* __restrict__ Q0,
                                               float* __restrict__ ws) {
  __shared__ float sred[4];
  int tid = threadIdx.x;
  int b = blockIdx.x;
  int wave = tid >> 6, lane = tid & 63;
  if (b < 24) {
    int m = b / 3, d = b % 3;
    const float* src = Vs + (size_t)(m*3 + d) * Nv;
    float s = 0.f;
    for (int n = tid; n < Nv; n += 256) s += src[n];
    s = wave_red_sum(s);
    if (lane == 0) sred[wave] = s;
    __syncthreads();
    if (tid == 0) {
      float tot = sred[0]+sred[1]+sred[2]+sred[3];
      ws[WS_T + m*3 + d] = -tot / (float)Nv;
    }
    if (d == 0 && tid < 9) {
      ws[WS_R + m*9 + tid] = (tid==0||tid==4||tid==8) ? 1.f : 0.f;
    }
  } else {
    float s = (tid < Kv) ? Q0[tid] : 0.f;
    s = wave_red_sum(s);
    if (lane == 0) sred[wave] = s;
    __syncthreads();
    if (tid == 0) {
      float mq = (sred[0]+sred[1]+sred[2]+sred[3]) / (float)Kv;
      ws[WS_BETA] = GAMMA_C * mq * sqrtf(mq);
    }
    if (tid < Kv) ws[WS_Q + tid] = Q0[tid];
    for (int i = tid; i < Kv*3; i += 256) ws[WS_X + i] = X0[i];
    for (int i = tid; i < ACCSZ; i += 256) ws[WS_ACC + i] = 0.f;
  }
}

// ---- fp32 Jacobi rotation, COMPILE-TIME pair, named scalars only.
#define JROTF(app,aqq,apq,apr,aqr, vp0,vp1,vp2, vq0,vq1,vq2) do {           \
    float tau_ = (aqq - app) * __builtin_amdgcn_rcpf(2.0f*apq);             \
    float tt_ = __builtin_amdgcn_rcpf(fabsf(tau_) +                         \
                   __builtin_amdgcn_sqrtf(fmaf(tau_,tau_,1.0f)));           \
    tt_ = (tau_ < 0.0f) ? -tt_ : tt_;                                       \
    tt_ = (apq == 0.0f) ? 0.0f : tt_;                                       \
    float c_ = __builtin_amdgcn_rsqf(fmaf(tt_,tt_,1.0f)), s_ = tt_*c_;      \
    float papq_ = apq;                                                      \
    app = fmaf(-tt_,papq_,app); aqq = fmaf(tt_,papq_,aqq); apq = 0.0f;      \
    float tp_ = apr, tq_ = aqr;                                             \
    apr = c_*tp_ - s_*tq_; aqr = s_*tp_ + c_*tq_;                           \
    tp_=vp0; tq_=vq0; vp0=c_*tp_-s_*tq_; vq0=s_*tp_+c_*tq_;                 \
    tp_=vp1; tq_=vq1; vp1=c_*tp_-s_*tq_; vq1=s_*tp_+c_*tq_;                 \
    tp_=vp2; tq_=vq2; vp2=c_*tp_-s_*tq_; vq2=s_*tp_+c_*tq_;                 \
  } while(0)

#define CSWAP3F(la,lb, a0,a1,a2, b0,b1,b2) do {                             \
    if (la < lb) { float t_;                                                \
      t_=la; la=lb; lb=t_; t_=a0; a0=b0; b0=t_;                             \
      t_=a1; a1=b1; b1=t_; t_=a2; a2=b2; b2=t_; }                           \
  } while(0)

// ---- redundant small update for iteration `itprev` from acc -> sX/sQ/sR/sT.
// Runs identically in every block. Contains one internal __syncthreads;
// caller must __syncthreads() after before reading other threads' sX/sQ.
template<int ITPREV>
__device__ __forceinline__ void small_update(const float* __restrict__ acc,
                                             const float* __restrict__ ws,
                                             int tid,
                                             float (*sX)[3], float* sQ,
                                             float (*sR)[9], float (*sT)[3],
                                             float* sTn) {
  const int k = tid;
  float lk[Mv], w0v[Mv], w1v[Mv], w2v[Mv], hk[Mv];
  #pragma unroll
  for (int mm=0;mm<Mv;mm++) {
    lk[mm]  = acc[AC_L + mm*Kv + k];
    w0v[mm] = acc[AC_W + (mm*3+0)*Kv + k];
    w1v[mm] = acc[AC_W + (mm*3+1)*Kv + k];
    w2v[mm] = acc[AC_W + (mm*3+2)*Kv + k];
    hk[mm]  = acc[AC_H + mm*Kv + k];
  }
  float xp0 = 0.f, xp1 = 0.f, xp2 = 0.f;
  if (ITPREV <= 1) {
    xp0 = ws[WS_X + k*3+0]; xp1 = ws[WS_X + k*3+1]; xp2 = ws[WS_X + k*3+2];
  }

  if (tid < Mv) {
    int mm = tid;
    const float* st = acc + AC_STATS + mm*16;
    float s0=st[0], s1=st[1], s2v=st[2], s3=st[3], s4=st[4], s5=st[5],
          s6=st[6], s7=st[7], s8=st[8], s9=st[9], s10=st[10], s11=st[11],
          s12=st[12], s13=st[13], s14=st[14], s15=st[15];
    float z = s0;
    float mX0 = s1, mX1 = s2v, mX2 = s3;
    float mW0 = s4, mW1 = s5, mW2 = s6;
    float iz = __builtin_amdgcn_rcpf(z);
    float P00 = s7  - mX0*mW0*iz;
    float P01 = s8  - mX0*mW1*iz;
    float P02 = s9  - mX0*mW2*iz;
    float P10 = s10 - mX1*mW0*iz;
    float P11 = s11 - mX1*mW1*iz;
    float P12 = s12 - mX1*mW2*iz;
    float P20 = s13 - mX2*mW0*iz;
    float P21 = s14 - mX2*mW1*iz;
    float P22 = s15 - mX2*mW2*iz;
    float a00 = P00*P00 + P10*P10 + P20*P20;
    float a01 = P00*P01 + P10*P11 + P20*P21;
    float a02 = P00*P02 + P10*P12 + P20*P22;
    float a11 = P01*P01 + P11*P11 + P21*P21;
    float a12 = P01*P02 + P11*P12 + P21*P22;
    float a22 = P02*P02 + P12*P12 + P22*P22;
    float v00=1, v01=0, v02=0, v10=0, v11=1, v12=0, v20=0, v21=0, v22=1;
    #pragma unroll 1
    for (int sweep = 0; sweep < 8; sweep++) {
      JROTF(a00,a11,a01, a02,a12, v00,v10,v20, v01,v11,v21);
      JROTF(a00,a22,a02, a01,a12, v00,v10,v20, v02,v12,v22);
      JROTF(a11,a22,a12, a01,a02, v01,v11,v21, v02,v12,v22);
    }
    float l0 = a00, l1 = a11, l2 = a22;
    CSWAP3F(l0,l1, v00,v10,v20, v01,v11,v21);
    CSWAP3F(l1,l2, v01,v11,v21, v02,v12,v22);
    CSWAP3F(l0,l1, v00,v10,v20, v01,v11,v21);
    float detP = P00*(P11*P22-P12*P21) - P01*(P10*P22-P12*P20)
               + P02*(P10*P21-P11*P20);
    float s2d = (detP < 0.0f) ? -1.0f : 1.0f;
    float tiny = 1e-18f*l0 + 1e-30f;
    float w0i = __builtin_amdgcn_rsqf(fmaxf(l0,tiny));
    float w1i = __builtin_amdgcn_rsqf(fmaxf(l1,tiny));
    float w2i = s2d*__builtin_amdgcn_rsqf(fmaxf(l2,tiny));
    float M00 = w0i*v00*v00 + w1i*v01*v01 + w2i*v02*v02;
    float M01 = w0i*v00*v10 + w1i*v01*v11 + w2i*v02*v12;
    float M02 = w0i*v00*v20 + w1i*v01*v21 + w2i*v02*v22;
    float M11 = w0i*v10*v10 + w1i*v11*v11 + w2i*v12*v12;
    float M12 = w0i*v10*v20 + w1i*v11*v21 + w2i*v12*v22;
    float M22 = w0i*v20*v20 + w1i*v21*v21 + w2i*v22*v22;
    float R00n = P00*M00 + P01*M01 + P02*M02;
    float R01n = P00*M01 + P01*M11 + P02*M12;
    float R02n = P00*M02 + P01*M12 + P02*M22;
    float R10n = P10*M00 + P11*M01 + P12*M02;
    float R11n = P10*M01 + P11*M11 + P12*M12;
    float R12n = P10*M02 + P11*M12 + P12*M22;
    float R20n = P20*M00 + P21*M01 + P22*M02;
    float R21n = P20*M01 + P21*M11 + P22*M12;
    float R22n = P20*M02 + P21*M12 + P22*M22;
    float tm0 = (mX0 - (R00n*mW0 + R01n*mW1 + R02n*mW2))*iz;
    float tm1 = (mX1 - (R10n*mW0 + R11n*mW1 + R12n*mW2))*iz;
    float tm2 = (mX2 - (R20n*mW0 + R21n*mW1 + R22n*mW2))*iz;
    sR[mm][0]=R00n; sR[mm][1]=R01n; sR[mm][2]=R02n;
    sR[mm][3]=R10n; sR[mm][4]=R11n; sR[mm][5]=R12n;
    sR[mm][6]=R20n; sR[mm][7]=R21n; sR[mm][8]=R22n;
    sT[mm][0]=tm0; sT[mm][1]=tm1; sT[mm][2]=tm2;
    sTn[mm] = tm0*tm0 + tm1*tm1 + tm2*tm2;
  }
  __syncthreads();
  {
    float den = 0.f, Xn0=0.f, Xn1=0.f, Xn2=0.f, S2=0.f;
    #pragma unroll
    for (int mm=0;mm<Mv;mm++) {
      float r0 = sR[mm][0]*w0v[mm] + sR[mm][1]*w1v[mm] + sR[mm][2]*w2v[mm];
      float r1 = sR[mm][3]*w0v[mm] + sR[mm][4]*w1v[mm] + sR[mm][5]*w2v[mm];
      float r2 = sR[mm][6]*w0v[mm] + sR[mm][7]*w1v[mm] + sR[mm][8]*w2v[mm];
      float tt0 = sT[mm][0], tt1 = sT[mm][1], tt2 = sT[mm][2];
      den += lk[mm];
      Xn0 += r0 + tt0*lk[mm]; Xn1 += r1 + tt1*lk[mm]; Xn2 += r2 + tt2*lk[mm];
      S2  += hk[mm] + 2.f*(tt0*r0+tt1*r1+tt2*r2) + sTn[mm]*lk[mm];
    }
    float x0, x1, x2;
    if (ITPREV > 1) { float inv = __builtin_amdgcn_rcpf(den);
                      x0=Xn0*inv; x1=Xn1*inv; x2=Xn2*inv; }
    else            { x0=xp0; x1=xp1; x2=xp2; }
    float wn = S2 + (x0*x0+x1*x1+x2*x2)*den - 2.f*(x0*Xn0+x1*Xn1+x2*Xn2);
    float qn = 3.f*den / (wn + 3.f*den*EPSILON_C);
    sX[k][0]=x0; sX[k][1]=x1; sX[k][2]=x2;
    sQ[k] = qn;
  }
}

// ------------------------------------------- one-iteration kernel (512 blocks)
// Templated on IT so (a) rocprof reports each iteration as a distinct kernel
// (p_iter<0> has NO prologue at compile time -> the <1..5> minus <0> delta
// directly measures the post-atomic acc read-back cost), (b) branches fold.
template<int IT>
__global__ __launch_bounds__(256) void p_iter(const float* __restrict__ Vs,
                                              float* __restrict__ ws) {
  __shared__ float sb[4][5][Kv]; // 20 KB
  __shared__ float st4[4][16];
  __shared__ float sX[Kv][3];
  __shared__ float sQ[Kv];
  __shared__ float sR[Mv][9];
  __shared__ float sT[Mv][3];
  __shared__ float sTn[Mv];

  int tid  = threadIdx.x;
  int wave = tid >> 6, lane = tid & 63;
  int bid  = blockIdx.x;
  int m    = bid / BPM;
  int blk  = bid % BPM;
  int wid  = blk*4 + wave;
  const int k = tid;

  float* acc  = ws + WS_ACC + (IT % 3)*ACCSZ;
  float* accz = ws + WS_ACC + ((IT+1) % 3)*ACCSZ;
  float beta = ws[WS_BETA];

  if (IT == 0) {
    if (tid < 72) ((float*)sR)[tid] = ws[WS_R + tid];
    if (tid < 24) ((float*)sT)[tid] = ws[WS_T + tid];
    sX[k][0] = ws[WS_X + 3*k+0];
    sX[k][1] = ws[WS_X + 3*k+1];
    sX[k][2] = ws[WS_X + 3*k+2];
    sQ[k]    = ws[WS_Q + k];
  } else {
    const float* accp = ws + WS_ACC + ((IT+2) % 3)*ACCSZ;  // (IT-1)%3
    small_update<(IT > 0) ? (IT-1) : 0>(accp, ws, tid, sX, sQ, sR, sT, sTn);
  }
  __syncthreads();

  // partitioned zero of buffer (IT+1)%3
  { int base = bid*21;
    if (tid < 21 && base + tid < ACCSZ) accz[base + tid] = 0.f; }

  // ---- phase A
  float R00=sR[m][0],R01=sR[m][1],R02=sR[m][2];
  float R10=sR[m][3],R11=sR[m][4],R12=sR[m][5];
  float R20=sR[m][6],R21=sR[m][7],R22=sR[m][8];
  float t0=sT[m][0], t1=sT[m][1], t2=sT[m][2];
  float kXx[4],kXy[4],kXz[4],kA[4],kB[4],kQ[4],kQ32[4];
  #pragma unroll
  for (int j=0;j<4;j++) {
    int kk = lane + 64*j;
    float xx = sX[kk][0], xy = sX[kk][1], xz = sX[kk][2];
    float q  = sQ[kk];
    kXx[j]=xx; kXy[j]=xy; kXz[j]=xz;
    kA[j]  = -0.5f*q;
    kB[j]  = kA[j]*(xx*xx+xy*xy+xz*xz);
    kQ[j]  = q;
    kQ32[j]= q*sqrtf(q);
  }
  float aL[4]={0,0,0,0}, aWx[4]={0,0,0,0}, aWy[4]={0,0,0,0},
        aWz[4]={0,0,0,0}, aH[4]={0,0,0,0};
  const float* V0 = Vs + (size_t)(m*3+0)*Nv;
  const float* V1 = Vs + (size_t)(m*3+1)*Nv;
  const float* V2 = Vs + (size_t)(m*3+2)*Nv;
  for (int n = wid; n < Nv; n += 256) {
    float vx = V0[n], vy = V1[n], vz = V2[n];
    float px = fmaf(R00,vx, fmaf(R01,vy, fmaf(R02,vz, t0)));
    float py = fmaf(R10,vx, fmaf(R11,vy, fmaf(R12,vz, t1)));
    float pz = fmaf(R20,vx, fmaf(R21,vy, fmaf(R22,vz, t2)));
    float tvn = fmaf(px,px, fmaf(py,py, pz*pz));
    float vn  = fmaf(vx,vx, fmaf(vy,vy, vz*vz));
    float ap[4]; float s = 0.f;
    #pragma unroll
    for (int j=0;j<4;j++) {
      float dot = fmaf(px,kXx[j], fmaf(py,kXy[j], pz*kXz[j]));
      float arg = fmaf(kQ[j], dot, fmaf(kA[j], tvn, kB[j]));
      float e = __expf(arg)*kQ32[j];
      ap[j] = e; s += e;
    }
    float S = wave_red_sum(s);
    float inv = __builtin_amdgcn_rcpf(S + beta);
    #pragma unroll
    for (int j=0;j<4;j++) {
      float a = ap[j]*inv;
      aL[j] += a;
      aWx[j] = fmaf(a,vx,aWx[j]);
      aWy[j] = fmaf(a,vy,aWy[j]);
      aWz[j] = fmaf(a,vz,aWz[j]);
      aH[j]  = fmaf(a,vn,aH[j]);
    }
  }
  #pragma unroll
  for (int j=0;j<4;j++) {
    int kk = lane + 64*j;
    sb[wave][0][kk]=aL[j];  sb[wave][1][kk]=aWx[j]; sb[wave][2][kk]=aWy[j];
    sb[wave][3][kk]=aWz[j]; sb[wave][4][kk]=aH[j];
  }
  __syncthreads();
  // block-permuted column: breaks cross-block same-address atomic pile-up
  const int k2 = (tid + 4*blk) & (Kv-1);
  float vL  = sb[0][0][k2]+sb[1][0][k2]+sb[2][0][k2]+sb[3][0][k2];
  float vWx = sb[0][1][k2]+sb[1][1][k2]+sb[2][1][k2]+sb[3][1][k2];
  float vWy = sb[0][2][k2]+sb[1][2][k2]+sb[2][2][k2]+sb[3][2][k2];
  float vWz = sb[0][3][k2]+sb[1][3][k2]+sb[2][3][k2]+sb[3][3][k2];
  float vH  = sb[0][4][k2]+sb[1][4][k2]+sb[2][4][k2]+sb[3][4][k2];
  atomicAdd(&acc[AC_L + m*Kv + k2], vL);
  atomicAdd(&acc[AC_W + (m*3+0)*Kv + k2], vWx);
  atomicAdd(&acc[AC_W + (m*3+1)*Kv + k2], vWy);
  atomicAdd(&acc[AC_W + (m*3+2)*Kv + k2], vWz);
  atomicAdd(&acc[AC_H + m*Kv + k2], vH);
  {
    float q  = sQ[k2];
    float x0 = sX[k2][0], x1 = sX[k2][1], x2 = sX[k2][2];
    float bk = vL*q;
    float sw0 = vWx*q, sw1 = vWy*q, sw2 = vWz*q;
    float pr[16];
    pr[0]=bk;  pr[1]=bk*x0; pr[2]=bk*x1; pr[3]=bk*x2;
    pr[4]=sw0; pr[5]=sw1;   pr[6]=sw2;
    pr[7]=sw0*x0;  pr[8]=sw1*x0;  pr[9]=sw2*x0;
    pr[10]=sw0*x1; pr[11]=sw1*x1; pr[12]=sw2*x1;
    pr[13]=sw0*x2; pr[14]=sw1*x2; pr[15]=sw2*x2;
    float red[16];
    #pragma unroll
    for (int v2=0; v2<16; v2++) red[v2] = wave_red_sum(pr[v2]);
    if (lane == 0) {
      #pragma unroll
      for (int v2=0; v2<16; v2++) st4[wave][v2] = red[v2];
    }
    __syncthreads();
    if (tid < 16)
      atomicAdd(&acc[AC_STATS + m*16 + ((tid + blk) & 15)],
                st4[0][(tid+blk)&15]+st4[1][(tid+blk)&15]+
                st4[2][(tid+blk)&15]+st4[3][(tid+blk)&15]);
  }
}

// ------------------------------- final: prologue finalizes iter 5, then write
#define OUT_TOTAL (Mv*3*Nv + 72 + 24 + Kv*3)
__global__ __launch_bounds__(256) void p3_final(const float* __restrict__ Vs,
                                                const float* __restrict__ ws,
                                                float* __restrict__ out) {
  __shared__ float sX[Kv][3];
  __shared__ float sQ[Kv];
  __shared__ float sR[Mv][9];
  __shared__ float sT[Mv][3];
  __shared__ float sTn[Mv];
  int tid = threadIdx.x;
  const float* acc = ws + WS_ACC + ((NITER-1) % 3)*ACCSZ;
  small_update<NITER-1>(acc, ws, tid, sX, sQ, sR, sT, sTn);
  __syncthreads();

  for (int idx = blockIdx.x*256 + tid; idx < OUT_TOTAL; idx += 256*256) {
    if (idx < Mv*3*Nv) {
      int m = idx / (3*Nv);
      int r = idx % (3*Nv);
      int d = r / Nv;
      int n = r % Nv;
      float vx = Vs[(size_t)(m*3+0)*Nv + n];
      float vy = Vs[(size_t)(m*3+1)*Nv + n];
      float vz = Vs[(size_t)(m*3+2)*Nv + n];
      out[idx] = fmaf(sR[m][d*3+0],vx,
                 fmaf(sR[m][d*3+1],vy,
                 fmaf(sR[m][d*3+2],vz, sT[m][d])));
    } else {
      int j = idx - Mv*3*Nv;
      float v;
      if (j < 72)      v = ((float*)sR)[j];
      else if (j < 96) v = ((float*)sT)[j-72];
      else             v = ((float*)sX)[j-96];
      out[idx] = v;
    }
  }
}

extern "C" void kernel_launch(void* const* d_in, const int* in_sizes, int n_in,
                              void* d_out, int out_size, void* d_ws, size_t ws_size,
                              hipStream_t stream) {
  const float* Vs = (const float*)d_in[0];
  const float* X0 = (const float*)d_in[1];
  const float* Q0 = (const float*)d_in[2];
  float* out = (float*)d_out;
  float* ws  = (float*)d_ws;

  p0_init<<<25, 256, 0, stream>>>(Vs, X0, Q0, ws);
  p_iter<0><<<NBLK, 256, 0, stream>>>(Vs, ws);
  p_iter<1><<<NBLK, 256, 0, stream>>>(Vs, ws);
  p_iter<2><<<NBLK, 256, 0, stream>>>(Vs, ws);
  p_iter<3><<<NBLK, 256, 0, stream>>>(Vs, ws);
  p_iter<4><<<NBLK, 256, 0, stream>>>(Vs, ws);
  p_iter<5><<<NBLK, 256, 0, stream>>>(Vs, ws);
  p3_final<<<256, 256, 0, stream>>>(Vs, ws, out);
}